// Round 2
// baseline (265.474 us; speedup 1.0000x reference)
//
#include <hip/hip_runtime.h>
#include <cstddef>

#define D_  32
#define N_  1024
#define T_  256
#define NT_ 1280
#define B_  32

// rows per block; must divide 1024 so seg_i is block-uniform
#define RPB 16
// 320 threads = 5 waves: thread t owns output float4 at col t*4.
// Waves 0-3 -> cols < 1024 (seg_j=0), wave 4 -> cols >= 1024 (seg_j=1):
// every seg select below is wave-uniform.
#define THR 320

// Single fused kernel: each block owns a [16 x 1280] output slab of one batch.
// It recomputes the tiny projection work it needs (LDS-staged), so there is no
// workspace round-trip, no second launch, no inter-kernel dependency stall.
// rel(si,sj): ss=0 (0,0), tt=1 (1,1), st=2 (0,1), ts=3 (1,0).

__device__ __forceinline__ float fast_tanh(float x) {
    // tanh(x) = 1 - 2/(e^{2x}+1); saturates to +-1, no NaN paths. err ~1e-6.
    float e = __expf(2.0f * x);
    return 1.0f - 2.0f * __builtin_amdgcn_rcpf(e + 1.0f);
}

__device__ __forceinline__ float dot32(const float4* __restrict__ xv,
                                       const float* __restrict__ w) {
    const float4* wv = (const float4*)w;
    float a = 0.f;
    #pragma unroll
    for (int k = 0; k < D_ / 4; ++k) {
        float4 ww = wv[k];
        a = fmaf(xv[k].x, ww.x, a);
        a = fmaf(xv[k].y, ww.y, a);
        a = fmaf(xv[k].z, ww.z, a);
        a = fmaf(xv[k].w, ww.w, a);
    }
    return a;
}

__global__ __launch_bounds__(THR) void fused_kernel(
    const float* __restrict__ S,  const float* __restrict__ Tn,
    const float* __restrict__ Wr, const float* __restrict__ br,
    const float* __restrict__ Wm, const float* __restrict__ bm,
    float* __restrict__ out)
{
    __shared__ float  ca_s[NT_];     // col adj proj, this block's seg_i plane
    __shared__ float  cm_s[NT_];     // col mask proj
    __shared__ float2 ra_s[RPB];     // row adj proj (.x: seg_j=0, .y: seg_j=1), bias folded
    __shared__ float2 rm_s[RPB];     // row mask proj

    const int tid   = threadIdx.x;        // 0..319
    const int i0    = blockIdx.x * RPB;   // first output row
    const int b     = blockIdx.y;         // batch
    const int seg_i = (i0 >= N_);         // block-uniform (RPB | 1024)
    const int r0    = seg_i ? 3 : 0;      // rel(seg_i, 0): ts / ss
    const int r1    = seg_i ? 1 : 2;      // rel(seg_i, 1): tt / st

    // ---- phase 1: column projections (weight half [D:]) for all 1280 cols ----
    // thread t handles cols t, t+320, t+640, t+960. Boundary (j=1024) falls at
    // tid=64 within c=3 -> sj stays wave-uniform.
    #pragma unroll
    for (int c = 0; c < 4; ++c) {
        const int j  = tid + c * THR;
        const int sj = (j >= N_);
        const float* xj = sj ? (Tn + ((size_t)b * T_ + (j - N_)) * D_)
                             : (S  + ((size_t)b * N_ +  j      ) * D_);
        float4 xv[D_ / 4];
        #pragma unroll
        for (int k = 0; k < D_ / 4; ++k) xv[k] = ((const float4*)xj)[k];
        const int rc = sj ? r1 : r0;      // rel(seg_i, sj)
        ca_s[j] = dot32(xv, Wr + rc * 2 * D_ + D_);
        cm_s[j] = dot32(xv, Wm + rc * 2 * D_ + D_);
    }

    // ---- phase 2: row projections (weight half [:D]) for this block's rows ----
    // 64 threads (wave 0): thread = (row, quadrant). q: 0=ra.x 1=ra.y 2=rm.x 3=rm.y
    if (tid < RPB * 4) {
        const int r = tid >> 2, q = tid & 3;
        const int i = i0 + r;
        const float* xi = seg_i ? (Tn + ((size_t)b * T_ + (i - N_)) * D_)
                                : (S  + ((size_t)b * N_ +  i      ) * D_);
        float4 xv[D_ / 4];
        #pragma unroll
        for (int k = 0; k < D_ / 4; ++k) xv[k] = ((const float4*)xi)[k];
        const int rs = (q & 1) ? r1 : r0;           // rel(seg_i, slot)
        const float* W  = (q < 2) ? Wr : Wm;
        const float* bb = (q < 2) ? br : bm;
        const float v = dot32(xv, W + rs * 2 * D_) + bb[rs];
        float* dst = (q < 2) ? (float*)ra_s : (float*)rm_s;
        dst[r * 2 + (q & 1)] = v;
    }
    __syncthreads();

    // ---- phase 3: stream the 16 output rows (pure write stream) ----
    const int   seg_j = (tid >= 256);                       // wave-uniform
    const float4 ca = *(const float4*)&ca_s[tid * 4];       // loop-invariant
    const float4 cm = *(const float4*)&cm_s[tid * 4];
    float* orow = out + ((size_t)(b * NT_ + i0)) * NT_ + tid * 4;

    #pragma unroll
    for (int r = 0; r < RPB; ++r) {
        const float2 rav = ra_s[r];                         // LDS broadcast
        const float2 rmv = rm_s[r];
        const float  ra  = seg_j ? rav.y : rav.x;
        const float  rm  = seg_j ? rmv.y : rmv.x;
        float4 o;
        o.x = fast_tanh((ra + ca.x) * fmaxf(rm + cm.x, 0.f));
        o.y = fast_tanh((ra + ca.y) * fmaxf(rm + cm.y, 0.f));
        o.z = fast_tanh((ra + ca.z) * fmaxf(rm + cm.z, 0.f));
        o.w = fast_tanh((ra + ca.w) * fmaxf(rm + cm.w, 0.f));
        *(float4*)(orow + (size_t)r * NT_) = o;
    }
}

extern "C" void kernel_launch(void* const* d_in, const int* in_sizes, int n_in,
                              void* d_out, int out_size, void* d_ws, size_t ws_size,
                              hipStream_t stream) {
    const float* S  = (const float*)d_in[0];  // spatial_nodes  [32,1024,32]
    const float* Tn = (const float*)d_in[1];  // temporal_nodes [32,256,32]
    const float* Wr = (const float*)d_in[2];  // W_rel  [4,64]
    const float* br = (const float*)d_in[3];  // b_rel  [4]
    const float* Wm = (const float*)d_in[4];  // W_mask [4,64]
    const float* bm = (const float*)d_in[5];  // b_mask [4]
    float* out = (float*)d_out;               // [32,1280,1280] fp32

    fused_kernel<<<dim3(NT_ / RPB, B_), THR, 0, stream>>>(S, Tn, Wr, br, Wm, bm, out);
}

// Round 4
// 229.194 us; speedup vs baseline: 1.1583x; 1.1583x over previous
//
#include <hip/hip_runtime.h>
#include <cstddef>

#define D_  32
#define N_  1024
#define T_  256
#define NT_ 1280
#define B_  32

// d_ws float layout (total 327,680 floats = 1.31 MB):
//   RA [B][NT][2]  offset 0       row adj proj, slot=seg_j, bias folded
//   RM [B][NT][2]  offset 81920   row mask proj, slot=seg_j, bias folded
//   CA [2][B][NT]  offset 163840  col adj proj, plane=seg_i
//   CM [2][B][NT]  offset 245760  col mask proj, plane=seg_i
#define RA_OFF 0
#define RM_OFF (B_*NT_*2)
#define CA_OFF (2*B_*NT_*2)
#define CM_OFF (CA_OFF + 2*B_*NT_)

// rows per epilogue block; must divide 1024 so seg_i is block-uniform
#define RPB 16

typedef float f32x4 __attribute__((ext_vector_type(4)));

__device__ __forceinline__ float fast_tanh(float x) {
    // tanh(x) = 1 - 2/(e^{2x}+1); saturates to +-1, no NaN paths. err ~1e-6.
    float e = __expf(2.0f * x);
    return 1.0f - 2.0f * __builtin_amdgcn_rcpf(e + 1.0f);
}

__device__ __forceinline__ float dot32(const float4* __restrict__ xv,
                                       const float* __restrict__ w) {
    const float4* wv = (const float4*)w;
    float a = 0.f;
    #pragma unroll
    for (int k = 0; k < D_ / 4; ++k) {
        float4 ww = wv[k];
        a = fmaf(xv[k].x, ww.x, a);
        a = fmaf(xv[k].y, ww.y, a);
        a = fmaf(xv[k].z, ww.z, a);
        a = fmaf(xv[k].w, ww.w, a);
    }
    return a;
}

// Projection kernel, split halves: waves 0-1 of each block compute ROW
// projections for 128 nodes, waves 2-3 compute COL projections for the same
// 128 nodes (branch wave-uniform; features L1-hit for the second half).
// 2x the parallelism and half the dependent-FMA chain vs one-thread-all-8.
// rel(si,sj): ss=0 (0,0), tt=1 (1,1), st=2 (0,1), ts=3 (1,0).
__global__ __launch_bounds__(256) void proj_kernel(
    const float* __restrict__ S,  const float* __restrict__ Tn,
    const float* __restrict__ Wr, const float* __restrict__ br,
    const float* __restrict__ Wm, const float* __restrict__ bm,
    float* __restrict__ ws)
{
    const int lane = threadIdx.x & 127;               // node within group
    const int half = threadIdx.x >> 7;                // 0=row, 1=col (wave-uniform)
    const int idx  = blockIdx.x * 128 + lane;         // node 0..1279
    const int b    = blockIdx.y;
    const int seg  = (idx >= N_);
    const float* x = seg ? (Tn + ((size_t)b * T_ + (idx - N_)) * D_)
                         : (S  + ((size_t)b * N_ +  idx      ) * D_);
    float4 xv[D_ / 4];
    #pragma unroll
    for (int k = 0; k < D_ / 4; ++k) xv[k] = ((const float4*)x)[k];

    if (half == 0) {
        // --- ROW i (si=seg): slot sj=0 -> rel(seg,0); sj=1 -> rel(seg,1) ---
        const int rr0 = seg ? 3 : 0;     // ts / ss
        const int rr1 = seg ? 1 : 2;     // tt / st
        float* RA = ws + RA_OFF;  float* RM = ws + RM_OFF;
        const size_t ri = ((size_t)b * NT_ + idx) * 2;
        float2 rav, rmv;
        rav.x = dot32(xv, Wr + rr0 * 2 * D_) + br[rr0];   // row half [:D]
        rav.y = dot32(xv, Wr + rr1 * 2 * D_) + br[rr1];
        rmv.x = dot32(xv, Wm + rr0 * 2 * D_) + bm[rr0];
        rmv.y = dot32(xv, Wm + rr1 * 2 * D_) + bm[rr1];
        *(float2*)&RA[ri] = rav;
        *(float2*)&RM[ri] = rmv;
    } else {
        // --- COL j (sj=seg): plane si=0 -> rel(0,seg); si=1 -> rel(1,seg) ---
        const int rc0 = seg ? 2 : 0;     // st / ss
        const int rc1 = seg ? 1 : 3;     // tt / ts
        float* CA = ws + CA_OFF;  float* CM = ws + CM_OFF;
        const size_t ci = (size_t)b * NT_ + idx;
        CA[0 * B_ * NT_ + ci] = dot32(xv, Wr + rc0 * 2 * D_ + D_);  // col half [D:]
        CA[1 * B_ * NT_ + ci] = dot32(xv, Wr + rc1 * 2 * D_ + D_);
        CM[0 * B_ * NT_ + ci] = dot32(xv, Wm + rc0 * 2 * D_ + D_);
        CM[1 * B_ * NT_ + ci] = dot32(xv, Wm + rc1 * 2 * D_ + D_);
    }
}

// Streaming epilogue, RPB rows per block: 320 threads (5 waves); thread = one
// float4 column slot, reused across RPB consecutive rows. ca/cm hoisted once
// per block (seg_i block-uniform since RPB | 1024); full unroll gives each
// thread RPB independent float4 NONTEMPORAL stores (output is never re-read
// on device -> keep the 210 MB/iter store stream out of L2's way).
// Waves 0-3: seg_j=0; wave 4: seg_j=1 -> all selects wave-uniform.
__global__ __launch_bounds__(320) void epi_kernel(
    const float* __restrict__ ws, float* __restrict__ out)
{
    const int tid   = threadIdx.x;          // 0..319
    const int i0    = blockIdx.x * RPB;     // first row of this block
    const int b     = blockIdx.y;           // batch
    const int seg_i = (i0  >= N_);          // uniform per block
    const int seg_j = (tid >= 256) ? 1 : 0; // uniform per wave

    const float* RA = ws + RA_OFF;
    const float* RM = ws + RM_OFF;
    const float* CA = ws + CA_OFF;
    const float* CM = ws + CM_OFF;

    const int j = tid * 4;
    const size_t cbase = ((size_t)seg_i * B_ + b) * NT_ + j;
    const float4 ca = *(const float4*)&CA[cbase];
    const float4 cm = *(const float4*)&CM[cbase];

    const float2* RAp = (const float2*)&RA[((size_t)b * NT_ + i0) * 2];
    const float2* RMp = (const float2*)&RM[((size_t)b * NT_ + i0) * 2];
    float* orow = out + ((size_t)(b * NT_ + i0)) * NT_ + j;

    #pragma unroll
    for (int r = 0; r < RPB; ++r) {
        const float2 rav = RAp[r];
        const float2 rmv = RMp[r];
        const float  ra  = seg_j ? rav.y : rav.x;
        const float  rm  = seg_j ? rmv.y : rmv.x;
        f32x4 o;
        o.x = fast_tanh((ra + ca.x) * fmaxf(rm + cm.x, 0.f));
        o.y = fast_tanh((ra + ca.y) * fmaxf(rm + cm.y, 0.f));
        o.z = fast_tanh((ra + ca.z) * fmaxf(rm + cm.z, 0.f));
        o.w = fast_tanh((ra + ca.w) * fmaxf(rm + cm.w, 0.f));
        __builtin_nontemporal_store(o, (f32x4*)(orow + (size_t)r * NT_));
    }
}

extern "C" void kernel_launch(void* const* d_in, const int* in_sizes, int n_in,
                              void* d_out, int out_size, void* d_ws, size_t ws_size,
                              hipStream_t stream) {
    const float* S  = (const float*)d_in[0];  // spatial_nodes  [32,1024,32]
    const float* Tn = (const float*)d_in[1];  // temporal_nodes [32,256,32]
    const float* Wr = (const float*)d_in[2];  // W_rel  [4,64]
    const float* br = (const float*)d_in[3];  // b_rel  [4]
    const float* Wm = (const float*)d_in[4];  // W_mask [4,64]
    const float* bm = (const float*)d_in[5];  // b_mask [4]
    float* out = (float*)d_out;               // [32,1280,1280] fp32
    float* ws  = (float*)d_ws;                // uses 1.31 MB

    proj_kernel<<<dim3(NT_ / 128, B_), 256, 0, stream>>>(S, Tn, Wr, br, Wm, bm, ws);
    epi_kernel <<<dim3(NT_ / RPB, B_), 320, 0, stream>>>(ws, out);
}